// Round 10
// baseline (310.409 us; speedup 1.0000x reference)
//
#include <hip/hip_runtime.h>

#define DD 768
#define NCH 96
#define TPB 512          // 8 waves per main block
#define RPB 512          // rows (tokens) per main block
#define G 16             // rows per group
#define NGRP (RPB / G)   // 32 groups
#define FTH 768          // finish threads

typedef unsigned int u32;

// LDS (dynamic) layout for k_main, bytes:
//   accB  u32[NCH*384]   147456   (bf16 pair per word)
//   mcp   f32[NCH]          384
//   cnt   f32[NCH]          384
//   pstat f32[G*8*2]       1024
//   rstdA f32[G]             64
//   labA  i32[G]             64
#define LDS_BYTES (147456 + 384 + 384 + 1024 + 64 + 64)

__device__ __forceinline__ float wave_reduce_sum(float v) {
#pragma unroll
  for (int m = 32; m >= 1; m >>= 1) v += __shfl_xor(v, m, 64);
  return v;
}
__device__ __forceinline__ u32 bf2(float a, float b) {
  u32 ua = __float_as_uint(a); ua += 0x7fffu + ((ua >> 16) & 1u);
  u32 ub = __float_as_uint(b); ub += 0x7fffu + ((ub >> 16) & 1u);
  return (ua >> 16) | (ub & 0xffff0000u);
}
__device__ __forceinline__ float bflo(u32 u) { return __uint_as_float(u << 16); }
__device__ __forceinline__ float bfhi(u32 u) { return __uint_as_float(u & 0xffff0000u); }

// ---------- main: sequential read of x; per-block LDS bf16 codebook accumulator ----------
__global__ void __launch_bounds__(TPB) k_main(
    const float* __restrict__ x, const int* __restrict__ tgt, int n,
    u32* __restrict__ P16, float* __restrict__ Pm, float* __restrict__ Pc,
    float* __restrict__ gS, float* __restrict__ gpos, int* __restrict__ ctr) {
  extern __shared__ char smem[];
  u32*   accB  = (u32*)smem;
  float* mcp_s = (float*)(smem + 147456);
  float* cnt_s = mcp_s + NCH;
  float* pstat = cnt_s + NCH;            // [G][8][2]
  float* rstdA = pstat + G * 16;
  int*   labA  = (int*)(rstdA + G);

  int tid = threadIdx.x, w = tid >> 6, l = tid & 63, blk = blockIdx.x;
  for (int i = tid; i < NCH * 384; i += TPB) accB[i] = 0u;
  for (int i = tid; i < 2 * NCH; i += TPB) mcp_s[i] = 0.f;  // mcp + cnt contiguous
  if (blk == 0) {  // zero finish accumulators (consumed next dispatch)
    for (int i = tid; i < DD; i += TPB) gS[i] = 0.f;
    if (tid == 0) { gpos[0] = 0.f; ctr[0] = 0; }
  }
  __syncthreads();

  const float2* x2 = (const float2*)x;
  size_t rowbase = (size_t)blk * RPB;
  int col = 48 * w + l;          // word index within row (l < 48)
  bool act = (l < 48);

  float2 cur[G], nxt[G];
#pragma unroll
  for (int j = 0; j < G; ++j) {
    size_t r = rowbase + j;
    cur[j] = (act && r < (size_t)n) ? x2[r * 384 + col] : make_float2(0.f, 0.f);
  }

  for (int g = 0; g < NGRP; ++g) {
    size_t r0 = rowbase + (size_t)g * G;
    // per-row partials, 16 interleaved wave-reduces
    float s[G], q[G];
#pragma unroll
    for (int j = 0; j < G; ++j) {
      s[j] = cur[j].x + cur[j].y;
      q[j] = cur[j].x * cur[j].x + cur[j].y * cur[j].y;
    }
#pragma unroll
    for (int m = 32; m >= 1; m >>= 1) {
#pragma unroll
      for (int j = 0; j < G; ++j) {
        s[j] += __shfl_xor(s[j], m, 64);
        q[j] += __shfl_xor(q[j], m, 64);
      }
    }
    if (l == 0) {
#pragma unroll
      for (int j = 0; j < G; ++j) {
        pstat[(j * 8 + w) * 2]     = s[j];
        pstat[(j * 8 + w) * 2 + 1] = q[j];
      }
    }
    // issue next group's loads (latency hides under barriers + rstd + acc)
    if (g + 1 < NGRP) {
#pragma unroll
      for (int j = 0; j < G; ++j) {
        size_t r = r0 + G + j;
        nxt[j] = (act && r < (size_t)n) ? x2[r * 384 + col] : make_float2(0.f, 0.f);
      }
    }
    __syncthreads();
    if (w == 0 && l < G) {
      size_t r = r0 + l;
      float ss = 0.f, qq = 0.f;
#pragma unroll
      for (int k = 0; k < 8; ++k) {
        ss += pstat[(l * 8 + k) * 2];
        qq += pstat[(l * 8 + k) * 2 + 1];
      }
      float mu = ss * (1.f / DD);
      float rs = rsqrtf(qq * (1.f / DD) - mu * mu + 1e-5f);
      rstdA[l] = rs;
      int c = (r < (size_t)n) ? tgt[r] : -1;
      labA[l] = c;
      if (c >= 0) {
        atomicAdd(&mcp_s[c], rs * mu);
        atomicAdd(&cnt_s[c], 1.f);
      }
    }
    __syncthreads();
    // race-free bf16 RMW: lane owns one u32 word column across all labels
    if (act) {
#pragma unroll
      for (int j = 0; j < G; ++j) {
        int c = labA[j];
        if (c >= 0) {
          float rs = rstdA[j];
          u32* wp = &accB[c * 384 + col];
          u32 old = *wp;
          *wp = bf2(bflo(old) + rs * cur[j].x, bfhi(old) + rs * cur[j].y);
        }
      }
    }
#pragma unroll
    for (int j = 0; j < G; ++j) cur[j] = nxt[j];
  }

  __syncthreads();
  int nblk = gridDim.x;
  for (int i = tid; i < NCH * 384; i += TPB) {
    int c = i / 384, word = i % 384;
    P16[((size_t)c * nblk + blk) * 384 + word] = accB[i];
  }
  for (int c = tid; c < NCH; c += TPB) {
    Pm[c * nblk + blk] = mcp_s[c];
    Pc[c * nblk + blk] = cnt_s[c];
  }
}

// ---------- finish: 96 blocks x 768 threads; partial reduce + tail math ----------
__global__ void __launch_bounds__(FTH) k_finish(
    const float* __restrict__ dic, const float* __restrict__ wln,
    const float* __restrict__ bln, const u32* __restrict__ P16,
    const float* __restrict__ Pm, const float* __restrict__ Pc, int nblk,
    float* __restrict__ gS, float* __restrict__ gpos, int* __restrict__ counter,
    float* __restrict__ out) {
  __shared__ float ps[2][384][2];
  __shared__ float mcsh, ncsh;
  __shared__ float red[12][3];
  __shared__ float fin[2];
  __shared__ int dsh;
  int c = blockIdx.x, tid = threadIdx.x, lane = tid & 63, wid = tid >> 6;
  if (tid == 0) { mcsh = 0.f; ncsh = 0.f; }
  __syncthreads();

  int h = tid / 384, word = tid % 384;
  float lo = 0.f, hi = 0.f;
  const u32* base = P16 + (size_t)c * nblk * 384;
  int b0 = h * (nblk / 2), b1 = b0 + nblk / 2;
  for (int b = b0; b < b1; ++b) {
    u32 u = base[(size_t)b * 384 + word];
    lo += bflo(u); hi += bfhi(u);
  }
  ps[h][word][0] = lo; ps[h][word][1] = hi;
  float mpart = (tid < nblk) ? Pm[c * nblk + tid] : 0.f;
  float npart = (tid < nblk) ? Pc[c * nblk + tid] : 0.f;
  mpart = wave_reduce_sum(mpart);
  npart = wave_reduce_sum(npart);
  if (lane == 0) { atomicAdd(&mcsh, mpart); atomicAdd(&ncsh, npart); }
  __syncthreads();

  int d = tid;                 // 0..767
  int wd = d >> 1, par = d & 1;
  float S1 = ps[0][wd][par] + ps[1][wd][par];
  float mc = mcsh, nc = ncsh;
  float gg = dic[c * DD + d] + wln[d] * (S1 - mc) + nc * bln[d];
  float inv = 1.f / (nc + 1.f);
  float u = dic[c * DD + d] + 0.1f * gg * inv;

  float pacc = wave_reduce_sum(gg * gg);
  float usum = wave_reduce_sum(u);
  float usq  = wave_reduce_sum(u * u);
  if (lane == 0) { red[wid][0] = pacc; red[wid][1] = usum; red[wid][2] = usq; }
  __syncthreads();
  if (tid == 0) {
    float tp = 0.f, ts = 0.f, tq = 0.f;
    for (int i = 0; i < 12; ++i) { tp += red[i][0]; ts += red[i][1]; tq += red[i][2]; }
    atomicAdd(gpos, tp);
    float mu = ts * (1.f / DD);
    fin[0] = mu;
    fin[1] = rsqrtf(tq * (1.f / DD) - mu * mu + 1e-5f);
  }
  __syncthreads();
  if (c >= 1) {
    float sacc = (u - fin[0]) * fin[1] * wln[d] + bln[d];
    atomicAdd(&gS[d], sacc);
  }

  __threadfence();
  __syncthreads();
  if (tid == 0) dsh = (atomicAdd(counter, 1) == NCH - 1) ? 1 : 0;
  __syncthreads();
  if (dsh) {
    __threadfence();
    float t = gS[d];
    float nv = wave_reduce_sum(t * t);
    if (lane == 0) red[wid][0] = nv;
    __syncthreads();
    if (tid == 0) {
      float tot = 0.f;
      for (int i = 0; i < 12; ++i) tot += red[i][0];
      out[0] = (tot - gpos[0]) * (1.f / DD);
    }
  }
}

extern "C" void kernel_launch(void* const* d_in, const int* in_sizes, int n_in,
                              void* d_out, int out_size, void* d_ws, size_t ws_size,
                              hipStream_t stream) {
  (void)n_in; (void)out_size; (void)ws_size;
  const float* x   = (const float*)d_in[0];
  const float* dic = (const float*)d_in[1];
  const float* w   = (const float*)d_in[2];
  const float* b   = (const float*)d_in[3];
  const int*   tgt = (const int*)d_in[4];
  float* out = (float*)d_out;
  int N = in_sizes[4];  // tokens (B*S = 131072)

  int nblk = (N + RPB - 1) / RPB;  // 256

  char* ws = (char*)d_ws;
  float* gS   = (float*)(ws);                 // 3072 B
  float* gpos = (float*)(ws + 3072);
  int*   ctr  = (int*)(ws + 3076);
  float* Pm   = (float*)(ws + 4096);                          // 96*nblk*4
  float* Pc   = (float*)(ws + 4096 + (size_t)NCH * nblk * 4);
  u32*   P16  = (u32*)(ws + 4096 + 2 * (size_t)NCH * nblk * 4);  // 96*nblk*384*4

  hipFuncSetAttribute((const void*)k_main,
                      hipFuncAttributeMaxDynamicSharedMemorySize, LDS_BYTES);

  k_main<<<nblk, TPB, LDS_BYTES, stream>>>(x, tgt, N, P16, Pm, Pc, gS, gpos, ctr);
  k_finish<<<NCH, FTH, 0, stream>>>(dic, w, b, P16, Pm, Pc, nblk,
                                    gS, gpos, ctr, out);
}